// Round 2
// 207.801 us; speedup vs baseline: 1.1538x; 1.1538x over previous
//
#include <hip/hip_runtime.h>
#include <math.h>

// Problem constants: B=16, N=128, M=64, D=512, H=4, K=128, L=3
//
// Key identity: relu(x*y) = (x*y + |x|*|y|)/2  (exact in FP arithmetic).
// This converts every contraction over the [B,N,M,D] relu-hadamard tensor
// into plain fp32 GEMMs -- no per-m shuffle reductions, no atomics.
//
//   s[b,n,m,h]  = sum_d w[n,d]*(r[m,d]*v[h,d]/2) + |w[n,d]|*(|r[m,d]|*v[h,d]/2)
//   G[b,h,d]    = 1/2 * sum_m ( r[m,d]*P[m,d] + |r[m,d]|*Pa[m,d] )
//       where P = wts^T * w , Pa = wts^T * |w|   (contraction over n)

// Workspace layout (floats)
#define OFF_W   0                         // w  [B*N=2048][512]
#define OFF_R   (2048*512)                // r  [B*M=1024][512]
#define OFF_V   (OFF_R + 1024*512)        // v2 [H=4][512]  (0.5 * v)
#define OFF_S   (OFF_V + 2048)            // s/wts (in-place) [B][H][64 m][128 n]
#define OFF_G   (OFF_S + 16*4*64*128)     // G  [B][H][512]
#define OFF_SW  (OFF_G + 16*4*512)        // SW halves [B*H][2]
#define OFF_HM  (OFF_SW + 128)            // hm [B][512]
#define OFF_OS  (OFF_HM + 16*512)         // relu(final) [B][512]
// total: 2,148,416 floats = 8.6 MB

// ---------------------------------------------------------------------------
// Kernel 1: fused projections  w = word@Wn_w + Wn_b ; r = rel@Wr_w + Wr_b
// (unchanged from verified baseline)
// ---------------------------------------------------------------------------
__global__ __launch_bounds__(256) void proj_gemm(
    const float* __restrict__ word, const float* __restrict__ rel,
    const float* __restrict__ Wn_w, const float* __restrict__ Wn_b,
    const float* __restrict__ Wr_w, const float* __restrict__ Wr_b,
    float* __restrict__ ws)
{
    int blk = blockIdx.x;
    const float *A, *W, *bias;
    float* C;
    int rowTile, colTile;
    if (blk < 256) {
        A = word; W = Wn_w; bias = Wn_b; C = ws + OFF_W;
        rowTile = blk >> 3; colTile = blk & 7;
    } else {
        int b2 = blk - 256;
        A = rel; W = Wr_w; bias = Wr_b; C = ws + OFF_R;
        rowTile = b2 >> 3; colTile = b2 & 7;
    }
    const int row0 = rowTile * 64, col0 = colTile * 64;

    __shared__ float As[16][68];
    __shared__ float Bs[16][64];

    const int t  = threadIdx.x;
    const int tx = t & 15, ty = t >> 4;
    const int lr = t >> 2, lk = (t & 3) << 2;
    const int bk = t >> 4, bc = (t & 15) << 2;

    float acc[4][4] = {};

    for (int k0 = 0; k0 < 512; k0 += 16) {
        float4 a4 = *(const float4*)(A + (size_t)(row0 + lr) * 512 + k0 + lk);
        As[lk + 0][lr] = a4.x; As[lk + 1][lr] = a4.y;
        As[lk + 2][lr] = a4.z; As[lk + 3][lr] = a4.w;
        *(float4*)&Bs[bk][bc] = *(const float4*)(W + (size_t)(k0 + bk) * 512 + col0 + bc);
        __syncthreads();
        #pragma unroll
        for (int kk = 0; kk < 16; kk++) {
            float4 av = *(float4*)&As[kk][ty << 2];
            float4 bv = *(float4*)&Bs[kk][tx << 2];
            float aa[4] = {av.x, av.y, av.z, av.w};
            float bb[4] = {bv.x, bv.y, bv.z, bv.w};
            #pragma unroll
            for (int i = 0; i < 4; i++)
                #pragma unroll
                for (int j = 0; j < 4; j++)
                    acc[i][j] = fmaf(aa[i], bb[j], acc[i][j]);
        }
        __syncthreads();
    }
    float4 bv = *(const float4*)(bias + col0 + (tx << 2));
    float bb[4] = {bv.x, bv.y, bv.z, bv.w};
    #pragma unroll
    for (int i = 0; i < 4; i++) {
        float4 o;
        o.x = acc[i][0] + bb[0]; o.y = acc[i][1] + bb[1];
        o.z = acc[i][2] + bb[2]; o.w = acc[i][3] + bb[3];
        *(float4*)(C + (size_t)(row0 + (ty << 2) + i) * 512 + col0 + (tx << 2)) = o;
    }
}

// ---------------------------------------------------------------------------
// Kernel 2: v2[h,d] = 0.5 * sum_k lin_w[h,d,k] * score_w[h,k]
// (lin_b/score_b constants cancel in softmax; 0.5 folds the relu identity)
// ---------------------------------------------------------------------------
__global__ __launch_bounds__(256) void prep_v(
    const float* __restrict__ lin_w, const float* __restrict__ score_w,
    float* __restrict__ ws)
{
    int gid = blockIdx.x * 256 + threadIdx.x;  // 0..2047
    int h = gid >> 9, d = gid & 511;
    const float* lw = lin_w + (size_t)(h * 512 + d) * 128;
    const float* sw = score_w + h * 128;
    float acc = 0.f;
    #pragma unroll 4
    for (int k = 0; k < 128; k += 4) {
        float4 a = *(const float4*)(lw + k);
        float4 b = *(const float4*)(sw + k);
        acc = fmaf(a.x, b.x, acc); acc = fmaf(a.y, b.y, acc);
        acc = fmaf(a.z, b.z, acc); acc = fmaf(a.w, b.w, acc);
    }
    ws[OFF_V + h * 512 + d] = 0.5f * acc;
}

// ---------------------------------------------------------------------------
// Kernel 3: scores GEMM.  s[b][h][m][n] = w.(r*v2) + |w|.(|r|*v2) over d.
// grid = 16 b x 4 ntile x 4 mhtile = 256 blocks; tile 32n x 64mh; K=512, BK=16
// A (w,|w|) interleaved in LDS; B (r*v2, |r|*v2) formed on the fly.
// ---------------------------------------------------------------------------
__global__ __launch_bounds__(256) void scores_kernel(float* __restrict__ ws)
{
    const int blk = blockIdx.x;
    const int mhtile = blk & 3;
    const int ntile  = (blk >> 2) & 3;
    const int b      = blk >> 4;
    const int n0 = ntile * 32;
    const int m0 = mhtile * 16;

    const float* wbase = ws + OFF_W + (size_t)(b * 128) * 512;
    const float* rbase = ws + OFF_R + (size_t)(b * 64) * 512;
    float* sbase = ws + OFF_S + (size_t)(b * 4) * 8192;   // [h][m][n]

    __shared__ float v2s[2048];          // [h*512 + d]
    __shared__ float Asab[16][68];       // [k][2n] = (w, |w|) interleaved
    __shared__ float Bs[16][68];         // [k][m*4+h] = r*v2
    __shared__ float Ba[16][68];         //            = |r|*v2

    const int t = threadIdx.x;
    // stage v2 once
    #pragma unroll
    for (int i = 0; i < 2; i++) {
        int idx4 = t + i * 256;
        *(float4*)&v2s[idx4 * 4] = *(const float4*)(ws + OFF_V + idx4 * 4);
    }
    __syncthreads();

    const int tx = t & 15, ty = t >> 4;   // tx -> mh quad, ty -> n pair
    const int an = t >> 3;                // A stage: n row 0..31
    const int ak = (t & 7) * 2;           // A stage: k pair
    const int bk = t & 15;                // B stage: k
    const int bq = t >> 4;                // B stage: m-local 0..15

    float acc[2][4] = {};

    for (int k0 = 0; k0 < 512; k0 += 16) {
        // A tile: w[n0+an][k0+ak..+1] -> interleave (w,|w|)
        float2 a2 = *(const float2*)(wbase + (size_t)(n0 + an) * 512 + k0 + ak);
        Asab[ak    ][an * 2]     = a2.x;
        Asab[ak    ][an * 2 + 1] = fabsf(a2.x);
        Asab[ak + 1][an * 2]     = a2.y;
        Asab[ak + 1][an * 2 + 1] = fabsf(a2.y);
        // B tile: form r*v2 and |r|*v2
        float rv = rbase[(size_t)(m0 + bq) * 512 + k0 + bk];
        float ra = fabsf(rv);
        #pragma unroll
        for (int h = 0; h < 4; h++) {
            float vv = v2s[h * 512 + k0 + bk];
            Bs[bk][bq * 4 + h] = rv * vv;
            Ba[bk][bq * 4 + h] = ra * vv;
        }
        __syncthreads();
        #pragma unroll
        for (int kk = 0; kk < 16; kk++) {
            float4 a  = *(float4*)&Asab[kk][ty * 4];  // (w_n0,|w|_n0,w_n1,|w|_n1)
            float4 bs = *(float4*)&Bs[kk][tx * 4];
            float4 ba = *(float4*)&Ba[kk][tx * 4];
            float bsv[4] = {bs.x, bs.y, bs.z, bs.w};
            float bav[4] = {ba.x, ba.y, ba.z, ba.w};
            #pragma unroll
            for (int j = 0; j < 4; j++) {
                acc[0][j] = fmaf(a.x, bsv[j], acc[0][j]);
                acc[0][j] = fmaf(a.y, bav[j], acc[0][j]);
                acc[1][j] = fmaf(a.z, bsv[j], acc[1][j]);
                acc[1][j] = fmaf(a.w, bav[j], acc[1][j]);
            }
        }
        __syncthreads();
    }
    // store: local mh = tx*4+j -> m = m0+tx, h = j ; n = n0 + ty*2 + i
    #pragma unroll
    for (int i = 0; i < 2; i++)
        #pragma unroll
        for (int j = 0; j < 4; j++)
            sbase[((size_t)j * 64 + m0 + tx) * 128 + n0 + ty * 2 + i] = acc[i][j];
}

// ---------------------------------------------------------------------------
// Kernel 4: softmax over m (in-place in s) + mask + per-half SW sums
// grid = 64 (b*4+h) x 2 n-halves = 128 blocks
// ---------------------------------------------------------------------------
__global__ __launch_bounds__(256) void softmax_kernel(
    const float* __restrict__ mask, float* __restrict__ ws)
{
    const int blk = blockIdx.x;
    const int nh = blk & 1, bh = blk >> 1, b = bh >> 2;
    float* sbase = ws + OFF_S + (size_t)bh * 8192;   // [64 m][128 n]

    __shared__ float sl[64][68];
    __shared__ float maskl[64];

    const int t = threadIdx.x;
    if (t < 64) maskl[t] = mask[b * 64 + t];
    #pragma unroll
    for (int i = 0; i < 4; i++) {
        int idx4 = t + i * 256;              // 0..1023 (4096 floats)
        int row = idx4 >> 4, col = (idx4 & 15) * 4;
        *(float4*)&sl[row][col] = *(const float4*)(sbase + (size_t)row * 128 + nh * 64 + col);
    }
    __syncthreads();

    if (t < 64) {                            // wave 0: one column each
        const int n = t;
        float e[64];
        float mx = -1e30f;
        #pragma unroll
        for (int m = 0; m < 64; m++) { e[m] = sl[m][n]; mx = fmaxf(mx, e[m]); }
        float sum = 0.f;
        #pragma unroll
        for (int m = 0; m < 64; m++) { e[m] = expf(e[m] - mx); sum += e[m]; }
        float inv = 1.0f / sum;
        float colsum = 0.f;
        #pragma unroll
        for (int m = 0; m < 64; m++) {
            float wt = e[m] * inv * maskl[m];
            sl[m][n] = wt;
            colsum += wt;
        }
        #pragma unroll
        for (int off = 32; off > 0; off >>= 1)
            colsum += __shfl_xor(colsum, off);
        if (t == 0) ws[OFF_SW + blk] = colsum;   // SW half-sum
    }
    __syncthreads();
    #pragma unroll
    for (int i = 0; i < 4; i++) {
        int idx4 = t + i * 256;
        int row = idx4 >> 4, col = (idx4 & 15) * 4;
        *(float4*)(sbase + (size_t)row * 128 + nh * 64 + col) = *(float4*)&sl[row][col];
    }
}

// ---------------------------------------------------------------------------
// Kernel 5: G-step.  accC = wts^T.w, accA = wts^T.|w| (over n, K=128),
// epilogue: G[b,h,d] = 0.5 * sum_m ( r[m,d]*accC + |r[m,d]|*accA )
// grid = (b*4+h)*8 + dtile = 512 blocks; tile 64m x 64d; no atomics.
// ---------------------------------------------------------------------------
__global__ __launch_bounds__(256) void gstep_kernel(float* __restrict__ ws)
{
    const int blk = blockIdx.x;
    const int dtile = blk & 7, bh = blk >> 3;
    const int b = bh >> 2;
    const int d0 = dtile * 64;
    const float* wts   = ws + OFF_S + (size_t)bh * 8192;        // [m][n]
    const float* wbase = ws + OFF_W + (size_t)(b * 128) * 512;
    const float* rbase = ws + OFF_R + (size_t)(b * 64) * 512;

    __shared__ float As[16][68];   // [n][m]  (wts transposed)
    __shared__ float Bs[16][68];   // [n][d]  w
    __shared__ float Ba[16][68];   // [n][d]  |w|
    __shared__ float red[16][68];

    const int t = threadIdx.x;
    const int tx = t & 15, ty = t >> 4;
    const int am = t >> 2, an4 = (t & 3) * 4;     // A stage
    const int bn = t >> 4, bd4 = (t & 15) * 4;    // B stage

    float accC[4][4] = {}, accA[4][4] = {};

    for (int n0 = 0; n0 < 128; n0 += 16) {
        float4 a4 = *(const float4*)(wts + (size_t)am * 128 + n0 + an4);
        As[an4 + 0][am] = a4.x; As[an4 + 1][am] = a4.y;
        As[an4 + 2][am] = a4.z; As[an4 + 3][am] = a4.w;
        float4 b4 = *(const float4*)(wbase + (size_t)(n0 + bn) * 512 + d0 + bd4);
        *(float4*)&Bs[bn][bd4] = b4;
        float4 bb; bb.x = fabsf(b4.x); bb.y = fabsf(b4.y);
        bb.z = fabsf(b4.z); bb.w = fabsf(b4.w);
        *(float4*)&Ba[bn][bd4] = bb;
        __syncthreads();
        #pragma unroll
        for (int kk = 0; kk < 16; kk++) {
            float4 av  = *(float4*)&As[kk][ty * 4];
            float4 bv  = *(float4*)&Bs[kk][tx * 4];
            float4 bav = *(float4*)&Ba[kk][tx * 4];
            float av_[4]  = {av.x, av.y, av.z, av.w};
            float bv_[4]  = {bv.x, bv.y, bv.z, bv.w};
            float bav_[4] = {bav.x, bav.y, bav.z, bav.w};
            #pragma unroll
            for (int i = 0; i < 4; i++)
                #pragma unroll
                for (int j = 0; j < 4; j++) {
                    accC[i][j] = fmaf(av_[i], bv_[j],  accC[i][j]);
                    accA[i][j] = fmaf(av_[i], bav_[j], accA[i][j]);
                }
        }
        __syncthreads();
    }
    // epilogue: thread owns m = ty*4+i, d = d0 + tx*4+j
    float g0 = 0.f, g1 = 0.f, g2 = 0.f, g3 = 0.f;
    #pragma unroll
    for (int i = 0; i < 4; i++) {
        float4 rv = *(const float4*)(rbase + (size_t)(ty * 4 + i) * 512 + d0 + tx * 4);
        g0 = fmaf(rv.x, accC[i][0], g0); g0 = fmaf(fabsf(rv.x), accA[i][0], g0);
        g1 = fmaf(rv.y, accC[i][1], g1); g1 = fmaf(fabsf(rv.y), accA[i][1], g1);
        g2 = fmaf(rv.z, accC[i][2], g2); g2 = fmaf(fabsf(rv.z), accA[i][2], g2);
        g3 = fmaf(rv.w, accC[i][3], g3); g3 = fmaf(fabsf(rv.w), accA[i][3], g3);
    }
    float4 gg; gg.x = g0; gg.y = g1; gg.z = g2; gg.w = g3;
    *(float4*)&red[ty][tx * 4] = gg;
    __syncthreads();
    if (t < 64) {
        float s = 0.f;
        #pragma unroll
        for (int q = 0; q < 16; q++) s += red[q][t];
        ws[OFF_G + (size_t)bh * 512 + d0 + t] = 0.5f * s;
    }
}

// ---------------------------------------------------------------------------
// Kernel 6: headmean[b,h,k] = (G[b,h,:].lin_w[h,:,k] + lin_b[h,k]*SW[b,h])/128
// grid = 64 (b*4+h); 2 threads per k (d-split halves)
// ---------------------------------------------------------------------------
__global__ __launch_bounds__(256) void headmean_kernel(
    const float* __restrict__ lin_w, const float* __restrict__ lin_b,
    float* __restrict__ ws)
{
    const int bh = blockIdx.x, b = bh >> 2, h = bh & 3;
    __shared__ float Gs[512];
    __shared__ float red[128];
    const int t = threadIdx.x;
    Gs[t]       = ws[OFF_G + (size_t)bh * 512 + t];
    Gs[t + 256] = ws[OFF_G + (size_t)bh * 512 + t + 256];
    __syncthreads();
    const float SWv = ws[OFF_SW + bh * 2] + ws[OFF_SW + bh * 2 + 1];
    const int k = t & 127, half = t >> 7;
    const float* lwp = lin_w + ((size_t)h * 512 + half * 256) * 128 + k;
    const float* gp = Gs + half * 256;
    float acc = 0.f;
    #pragma unroll 8
    for (int d = 0; d < 256; d++)
        acc = fmaf(gp[d], lwp[(size_t)d * 128], acc);
    if (half) red[k] = acc;
    __syncthreads();
    if (!half) {
        float tot = acc + red[k] + lin_b[h * 128 + k] * SWv;
        ws[OFF_HM + (size_t)b * 512 + h * 128 + k] = tot * (1.0f / 128.0f);
    }
}

// ---------------------------------------------------------------------------
// Kernel 7: out = relu(hm @ final_w + final_b)
// grid = 16 b x 4 jtile = 64 blocks; 2 threads per j (d-split halves)
// ---------------------------------------------------------------------------
__global__ __launch_bounds__(256) void final_kernel(
    const float* __restrict__ final_w, const float* __restrict__ final_b,
    float* __restrict__ ws)
{
    const int blk = blockIdx.x, b = blk >> 2, jt = blk & 3;
    __shared__ float hs[512];
    __shared__ float red[128];
    const int t = threadIdx.x;
    hs[t]       = ws[OFF_HM + (size_t)b * 512 + t];
    hs[t + 256] = ws[OFF_HM + (size_t)b * 512 + t + 256];
    __syncthreads();
    const int k = t & 127, half = t >> 7;
    const int j = jt * 128 + k;
    const float* fwp = final_w + (size_t)(half * 256) * 512 + j;
    const float* hp = hs + half * 256;
    float acc = 0.f;
    #pragma unroll 8
    for (int d = 0; d < 256; d++)
        acc = fmaf(hp[d], fwp[(size_t)d * 512], acc);
    if (half) red[k] = acc;
    __syncthreads();
    if (!half) {
        float o = fmaxf(acc + red[k] + final_b[j], 0.f);
        ws[OFF_OS + (size_t)b * 512 + j] = o;
    }
}

// ---------------------------------------------------------------------------
// Kernel 8: logits = out @ fc_w + fc_b   (16 blocks x 192 threads)
// ---------------------------------------------------------------------------
__global__ __launch_bounds__(192) void logits_kernel(
    const float* __restrict__ fc_w, const float* __restrict__ fc_b,
    const float* __restrict__ ws, float* __restrict__ out)
{
    const int b = blockIdx.x, t = threadIdx.x;
    const int l = t >> 6, ln = t & 63;
    const float* os = ws + OFF_OS + (size_t)b * 512;
    float acc = 0.f;
    for (int i = ln; i < 512; i += 64)
        acc = fmaf(os[i], fc_w[i * 3 + l], acc);
    #pragma unroll
    for (int off = 32; off > 0; off >>= 1)
        acc += __shfl_xor(acc, off);
    if (ln == 0) out[b * 3 + l] = acc + fc_b[l];
}

// ---------------------------------------------------------------------------
extern "C" void kernel_launch(void* const* d_in, const int* in_sizes, int n_in,
                              void* d_out, int out_size, void* d_ws, size_t ws_size,
                              hipStream_t stream)
{
    const float* word    = (const float*)d_in[0];
    const float* rel     = (const float*)d_in[1];
    const float* mask    = (const float*)d_in[2];
    const float* Wn_w    = (const float*)d_in[3];
    const float* Wn_b    = (const float*)d_in[4];
    const float* Wr_w    = (const float*)d_in[5];
    const float* Wr_b    = (const float*)d_in[6];
    const float* lin_w   = (const float*)d_in[7];
    const float* lin_b   = (const float*)d_in[8];
    const float* score_w = (const float*)d_in[9];
    // d_in[10] score_b: cancels in softmax — unused
    const float* final_w = (const float*)d_in[11];
    const float* final_b = (const float*)d_in[12];
    const float* fc_w    = (const float*)d_in[13];
    const float* fc_b    = (const float*)d_in[14];
    float* ws  = (float*)d_ws;
    float* out = (float*)d_out;

    // No accumulators anywhere -> no memset needed (every ws word written
    // before read; poison-safe).
    proj_gemm<<<384, 256, 0, stream>>>(word, rel, Wn_w, Wn_b, Wr_w, Wr_b, ws);
    prep_v<<<8, 256, 0, stream>>>(lin_w, score_w, ws);
    scores_kernel<<<256, 256, 0, stream>>>(ws);
    softmax_kernel<<<128, 256, 0, stream>>>(mask, ws);
    gstep_kernel<<<512, 256, 0, stream>>>(ws);
    headmean_kernel<<<64, 256, 0, stream>>>(lin_w, lin_b, ws);
    final_kernel<<<64, 256, 0, stream>>>(final_w, final_b, ws);
    logits_kernel<<<16, 192, 0, stream>>>(fc_w, fc_b, ws, out);
}

// Round 3
// 191.169 us; speedup vs baseline: 1.2542x; 1.0870x over previous
//
#include <hip/hip_runtime.h>
#include <math.h>

// Problem constants: B=16, N=128, M=64, D=512, H=4, K=128, L=3
//
// relu(x*y) = (x*y + |x|*|y|)/2  (exact) -> every contraction over the
// [B,N,M,D] relu-hadamard tensor becomes a plain fp32 GEMM.
//
//   s[b,n,m,h] = sum_d w[n,d]*(r[m,d]*v2[h,d]) + |w[n,d]|*(|r[m,d]|*v2[h,d])
//                (v2 = v/2; lin_b/score_b cancel in softmax)
//   G[b,h,d]   = 1/2 * sum_m ( r[m,d]*accC[m,d] + |r[m,d]|*accA[m,d] )
//       accC = wts^T.w , accA = wts^T.|w|   (contraction over n)

// Workspace layout (floats)
#define OFF_W   0                         // w  [2048][512]
#define OFF_R   (2048*512)                // r  [1024][512]
#define OFF_V   (OFF_R + 1024*512)        // v2 [4][512]
#define OFF_S   (OFF_V + 2048)            // wts^T [64 bh][128 n][64 m]
#define OFF_G   (OFF_S + 64*8192)         // G  [64 bh][512]
#define OFF_SW  (OFF_G + 64*512)          // SW quarter-sums [64 bh][4]
#define OFF_HM  (OFF_SW + 256)            // hm [16 b][512]
// total: 2,140,416 floats = 8.56 MB

// ---------------------------------------------------------------------------
// Kernel 1: fused projections + prep_v
// blocks [0,256): w-GEMM, [256,384): r-GEMM, [384,392): v2 prep
// ---------------------------------------------------------------------------
__global__ __launch_bounds__(256) void proj_gemm(
    const float* __restrict__ word, const float* __restrict__ rel,
    const float* __restrict__ Wn_w, const float* __restrict__ Wn_b,
    const float* __restrict__ Wr_w, const float* __restrict__ Wr_b,
    const float* __restrict__ lin_w, const float* __restrict__ score_w,
    float* __restrict__ ws)
{
    int blk = blockIdx.x;
    if (blk >= 384) {
        // prep_v: v2[h][d] = 0.5 * sum_k lin_w[h,d,k]*score_w[h,k]
        int gid = (blk - 384) * 256 + threadIdx.x;   // 0..2047
        int h = gid >> 9, d = gid & 511;
        const float* lw = lin_w + (size_t)(h * 512 + d) * 128;
        const float* sw = score_w + h * 128;
        float acc = 0.f;
        #pragma unroll 4
        for (int k = 0; k < 128; k += 4) {
            float4 a = *(const float4*)(lw + k);
            float4 b = *(const float4*)(sw + k);
            acc = fmaf(a.x, b.x, acc); acc = fmaf(a.y, b.y, acc);
            acc = fmaf(a.z, b.z, acc); acc = fmaf(a.w, b.w, acc);
        }
        ws[OFF_V + h * 512 + d] = 0.5f * acc;
        return;
    }
    const float *A, *W, *bias;
    float* C;
    int rowTile, colTile;
    if (blk < 256) {
        A = word; W = Wn_w; bias = Wn_b; C = ws + OFF_W;
        rowTile = blk >> 3; colTile = blk & 7;
    } else {
        int b2 = blk - 256;
        A = rel; W = Wr_w; bias = Wr_b; C = ws + OFF_R;
        rowTile = b2 >> 3; colTile = b2 & 7;
    }
    const int row0 = rowTile * 64, col0 = colTile * 64;

    __shared__ float As[16][68];
    __shared__ float Bs[16][64];

    const int t  = threadIdx.x;
    const int tx = t & 15, ty = t >> 4;
    const int lr = t >> 2, lk = (t & 3) << 2;
    const int bk = t >> 4, bc = (t & 15) << 2;

    float acc[4][4] = {};

    for (int k0 = 0; k0 < 512; k0 += 16) {
        float4 a4 = *(const float4*)(A + (size_t)(row0 + lr) * 512 + k0 + lk);
        As[lk + 0][lr] = a4.x; As[lk + 1][lr] = a4.y;
        As[lk + 2][lr] = a4.z; As[lk + 3][lr] = a4.w;
        *(float4*)&Bs[bk][bc] = *(const float4*)(W + (size_t)(k0 + bk) * 512 + col0 + bc);
        __syncthreads();
        #pragma unroll
        for (int kk = 0; kk < 16; kk++) {
            float4 av = *(float4*)&As[kk][ty << 2];
            float4 bv = *(float4*)&Bs[kk][tx << 2];
            float aa[4] = {av.x, av.y, av.z, av.w};
            float bb[4] = {bv.x, bv.y, bv.z, bv.w};
            #pragma unroll
            for (int i = 0; i < 4; i++)
                #pragma unroll
                for (int j = 0; j < 4; j++)
                    acc[i][j] = fmaf(aa[i], bb[j], acc[i][j]);
        }
        __syncthreads();
    }
    float4 bv = *(const float4*)(bias + col0 + (tx << 2));
    float bb[4] = {bv.x, bv.y, bv.z, bv.w};
    #pragma unroll
    for (int i = 0; i < 4; i++) {
        float4 o;
        o.x = acc[i][0] + bb[0]; o.y = acc[i][1] + bb[1];
        o.z = acc[i][2] + bb[2]; o.w = acc[i][3] + bb[3];
        *(float4*)(C + (size_t)(row0 + (ty << 2) + i) * 512 + col0 + (tx << 2)) = o;
    }
}

// ---------------------------------------------------------------------------
// Kernel 2: scores GEMM + fused softmax.  grid = (b*4+h)*4+nq = 256 blocks.
// Tile 64m x 32n, K=512.  Block owns the full m-range -> in-LDS softmax.
// Writes wts TRANSPOSED [n][m] (gstep's A layout) + SW quarter sums.
// ---------------------------------------------------------------------------
__global__ __launch_bounds__(256) void scores_sm(
    const float* __restrict__ mask, float* __restrict__ ws)
{
    const int blk = blockIdx.x;
    const int nq = blk & 3, bh = blk >> 2, h = bh & 3, b = bh >> 2;
    const int n0 = nq * 32;

    const float* wbase = ws + OFF_W + (size_t)(b * 128) * 512;
    const float* rbase = ws + OFF_R + (size_t)(b * 64) * 512;
    float* wtsT = ws + OFF_S + (size_t)bh * 8192;   // [128 n][64 m]

    __shared__ float v2s[512];
    __shared__ float maskl[64];
    __shared__ float As[16][68], Aa[16][68];   // [k][m] : r*v2 , |r|*v2
    __shared__ float Bs[16][36], Ba[16][36];   // [k][n] : w , |w|
    __shared__ float sl[64][37];               // [m][n] scores -> exp
    __shared__ float invl[33];

    const int t = threadIdx.x;
    if (t < 128) *(float4*)&v2s[t * 4] = *(const float4*)(ws + OFF_V + h * 512 + t * 4);
    if (t < 64) maskl[t] = mask[b * 64 + t];
    __syncthreads();

    const int ty = t >> 4, tx = t & 15;          // compute: m-quad / n-pair
    const int am = t >> 2, akq = (t & 3) * 4;    // A stage
    const int bn = t >> 2, bkq = (t & 3) * 4;    // B stage (t<128)

    float acc[4][2] = {};

    for (int k0 = 0; k0 < 512; k0 += 16) {
        {
            float4 r4 = *(const float4*)(rbase + (size_t)am * 512 + k0 + akq);
            float4 vv = *(const float4*)&v2s[k0 + akq];
            As[akq + 0][am] = r4.x * vv.x; Aa[akq + 0][am] = fabsf(r4.x) * vv.x;
            As[akq + 1][am] = r4.y * vv.y; Aa[akq + 1][am] = fabsf(r4.y) * vv.y;
            As[akq + 2][am] = r4.z * vv.z; Aa[akq + 2][am] = fabsf(r4.z) * vv.z;
            As[akq + 3][am] = r4.w * vv.w; Aa[akq + 3][am] = fabsf(r4.w) * vv.w;
        }
        if (t < 128) {
            float4 w4 = *(const float4*)(wbase + (size_t)(n0 + bn) * 512 + k0 + bkq);
            Bs[bkq + 0][bn] = w4.x; Ba[bkq + 0][bn] = fabsf(w4.x);
            Bs[bkq + 1][bn] = w4.y; Ba[bkq + 1][bn] = fabsf(w4.y);
            Bs[bkq + 2][bn] = w4.z; Ba[bkq + 2][bn] = fabsf(w4.z);
            Bs[bkq + 3][bn] = w4.w; Ba[bkq + 3][bn] = fabsf(w4.w);
        }
        __syncthreads();
        #pragma unroll
        for (int kk = 0; kk < 16; kk++) {
            float4 a  = *(float4*)&As[kk][ty * 4];
            float4 aa = *(float4*)&Aa[kk][ty * 4];
            float2 bv  = *(float2*)&Bs[kk][tx * 2];
            float2 bav = *(float2*)&Ba[kk][tx * 2];
            float a_[4]  = {a.x, a.y, a.z, a.w};
            float aa_[4] = {aa.x, aa.y, aa.z, aa.w};
            #pragma unroll
            for (int i = 0; i < 4; i++) {
                acc[i][0] = fmaf(a_[i], bv.x,  acc[i][0]);
                acc[i][0] = fmaf(aa_[i], bav.x, acc[i][0]);
                acc[i][1] = fmaf(a_[i], bv.y,  acc[i][1]);
                acc[i][1] = fmaf(aa_[i], bav.y, acc[i][1]);
            }
        }
        __syncthreads();
    }
    #pragma unroll
    for (int i = 0; i < 4; i++) {
        sl[ty * 4 + i][tx * 2 + 0] = acc[i][0];
        sl[ty * 4 + i][tx * 2 + 1] = acc[i][1];
    }
    __syncthreads();

    // softmax over m, one column per lane (t<32)
    if (t < 32) {
        const int n = t;
        float mx = sl[0][n];
        #pragma unroll
        for (int m = 1; m < 64; m++) mx = fmaxf(mx, sl[m][n]);
        float esum = 0.f, emsum = 0.f;
        #pragma unroll
        for (int m = 0; m < 64; m++) {
            float e = expf(sl[m][n] - mx);
            sl[m][n] = e;
            esum += e;
            emsum = fmaf(e, maskl[m], emsum);
        }
        float inv = 1.0f / esum;
        invl[n] = inv;
        float swq = emsum * inv;
        #pragma unroll
        for (int off = 16; off > 0; off >>= 1)
            swq += __shfl_xor(swq, off);
        if (t == 0) ws[OFF_SW + bh * 4 + nq] = swq;
    }
    __syncthreads();

    // write wts^T[n][m] = e * inv * mask
    const int wn = t >> 3;            // 0..31
    const int wm = (t & 7) * 8;       // 0..56
    const float inv = invl[wn];
    float o[8];
    #pragma unroll
    for (int e2 = 0; e2 < 8; e2++)
        o[e2] = sl[wm + e2][wn] * inv * maskl[wm + e2];
    float4 o0; o0.x = o[0]; o0.y = o[1]; o0.z = o[2]; o0.w = o[3];
    float4 o1; o1.x = o[4]; o1.y = o[5]; o1.z = o[6]; o1.w = o[7];
    *(float4*)(wtsT + (size_t)(n0 + wn) * 64 + wm)     = o0;
    *(float4*)(wtsT + (size_t)(n0 + wn) * 64 + wm + 4) = o1;
}

// ---------------------------------------------------------------------------
// Kernel 3: G-step.  accC = wts^T.w, accA = wts^T.|w| (over n, K=128),
// epilogue: G[b,h,d] = 0.5 * sum_m ( r[m,d]*accC + |r[m,d]|*accA )
// grid = bh*8 + dtile = 512 blocks; tile 64m x 64d; no atomics.
// wts input is already [n][m] -> coalesced float4 A-staging.
// ---------------------------------------------------------------------------
__global__ __launch_bounds__(256) void gstep_kernel(float* __restrict__ ws)
{
    const int blk = blockIdx.x;
    const int dtile = blk & 7, bh = blk >> 3;
    const int b = bh >> 2;
    const int d0 = dtile * 64;
    const float* wtsT  = ws + OFF_S + (size_t)bh * 8192;        // [n][m]
    const float* wbase = ws + OFF_W + (size_t)(b * 128) * 512;
    const float* rbase = ws + OFF_R + (size_t)(b * 64) * 512;

    __shared__ float As[16][68];   // [n][m]
    __shared__ float Bs[16][68];   // [n][d]  w
    __shared__ float Ba[16][68];   // [n][d]  |w|
    __shared__ float red[16][68];

    const int t = threadIdx.x;
    const int tx = t & 15, ty = t >> 4;
    const int an_r = t >> 4, am4 = (t & 15) * 4;   // A stage (row n, m-quad)
    const int bn = t >> 4, bd4 = (t & 15) * 4;     // B stage

    float accC[4][4] = {}, accA[4][4] = {};

    for (int n0 = 0; n0 < 128; n0 += 16) {
        *(float4*)&As[an_r][am4] =
            *(const float4*)(wtsT + (size_t)(n0 + an_r) * 64 + am4);
        float4 b4 = *(const float4*)(wbase + (size_t)(n0 + bn) * 512 + d0 + bd4);
        *(float4*)&Bs[bn][bd4] = b4;
        float4 bb; bb.x = fabsf(b4.x); bb.y = fabsf(b4.y);
        bb.z = fabsf(b4.z); bb.w = fabsf(b4.w);
        *(float4*)&Ba[bn][bd4] = bb;
        __syncthreads();
        #pragma unroll
        for (int kk = 0; kk < 16; kk++) {
            float4 av  = *(float4*)&As[kk][ty * 4];
            float4 bv  = *(float4*)&Bs[kk][tx * 4];
            float4 bav = *(float4*)&Ba[kk][tx * 4];
            float av_[4]  = {av.x, av.y, av.z, av.w};
            float bv_[4]  = {bv.x, bv.y, bv.z, bv.w};
            float bav_[4] = {bav.x, bav.y, bav.z, bav.w};
            #pragma unroll
            for (int i = 0; i < 4; i++)
                #pragma unroll
                for (int j = 0; j < 4; j++) {
                    accC[i][j] = fmaf(av_[i], bv_[j],  accC[i][j]);
                    accA[i][j] = fmaf(av_[i], bav_[j], accA[i][j]);
                }
        }
        __syncthreads();
    }
    // epilogue: thread owns m = ty*4+i, d = d0 + tx*4+j
    float g0 = 0.f, g1 = 0.f, g2 = 0.f, g3 = 0.f;
    #pragma unroll
    for (int i = 0; i < 4; i++) {
        float4 rv = *(const float4*)(rbase + (size_t)(ty * 4 + i) * 512 + d0 + tx * 4);
        g0 = fmaf(rv.x, accC[i][0], g0); g0 = fmaf(fabsf(rv.x), accA[i][0], g0);
        g1 = fmaf(rv.y, accC[i][1], g1); g1 = fmaf(fabsf(rv.y), accA[i][1], g1);
        g2 = fmaf(rv.z, accC[i][2], g2); g2 = fmaf(fabsf(rv.z), accA[i][2], g2);
        g3 = fmaf(rv.w, accC[i][3], g3); g3 = fmaf(fabsf(rv.w), accA[i][3], g3);
    }
    float4 gg; gg.x = g0; gg.y = g1; gg.z = g2; gg.w = g3;
    *(float4*)&red[ty][tx * 4] = gg;
    __syncthreads();
    if (t < 64) {
        float s = 0.f;
        #pragma unroll
        for (int q = 0; q < 16; q++) s += red[q][t];
        ws[OFF_G + (size_t)bh * 512 + d0 + t] = 0.5f * s;
    }
}

// ---------------------------------------------------------------------------
// Kernel 4: headmean.  grid = bh*4 + kt = 256 blocks, 32 k each, 8-way d-split.
// hm[b, h*128+k] = ( sum_d G[bh][d]*lin_w[h,d,k] + lin_b[h,k]*SW[bh] ) / 128
// ---------------------------------------------------------------------------
__global__ __launch_bounds__(256) void headmean_kernel(
    const float* __restrict__ lin_w, const float* __restrict__ lin_b,
    float* __restrict__ ws)
{
    const int blk = blockIdx.x;
    const int kt = blk & 3, bh = blk >> 2, b = bh >> 2, h = bh & 3;
    const int t = threadIdx.x;
    const int dg = t >> 5, kk = t & 31;
    const int k = kt * 32 + kk;

    __shared__ float Gs[512];
    __shared__ float red[8][33];

    Gs[t]       = ws[OFF_G + (size_t)bh * 512 + t];
    Gs[t + 256] = ws[OFF_G + (size_t)bh * 512 + t + 256];
    __syncthreads();

    const float* lwp = lin_w + ((size_t)h * 512 + dg * 64) * 128 + k;
    const float* gp = Gs + dg * 64;
    float acc = 0.f;
    #pragma unroll 8
    for (int d = 0; d < 64; d++)
        acc = fmaf(gp[d], lwp[(size_t)d * 128], acc);
    red[dg][kk] = acc;
    __syncthreads();
    if (t < 32) {
        float s = 0.f;
        #pragma unroll
        for (int q = 0; q < 8; q++) s += red[q][t];
        const float SWv = ws[OFF_SW + bh * 4 + 0] + ws[OFF_SW + bh * 4 + 1]
                        + ws[OFF_SW + bh * 4 + 2] + ws[OFF_SW + bh * 4 + 3];
        s = fmaf(lin_b[h * 128 + kt * 32 + t], SWv, s);
        ws[OFF_HM + (size_t)b * 512 + h * 128 + kt * 32 + t] = s * (1.0f / 128.0f);
    }
}

// ---------------------------------------------------------------------------
// Kernel 5: final + fused logits.  grid = b*16 + jt = 256 blocks, 32 j each.
// os_j = relu(hm[b]. final_w[:,j] + final_b[j]);
// atomicAdd partial logits (out zeroed by memset; fc_b added by jt==0 blocks).
// ---------------------------------------------------------------------------
__global__ __launch_bounds__(256) void final_logits(
    const float* __restrict__ final_w, const float* __restrict__ final_b,
    const float* __restrict__ fc_w, const float* __restrict__ fc_b,
    const float* __restrict__ ws, float* __restrict__ out)
{
    const int blk = blockIdx.x;
    const int jt = blk & 15, b = blk >> 4;
    const int t = threadIdx.x;
    const int dg = t >> 5, jj = t & 31;
    const int j = jt * 32 + jj;

    __shared__ float hs[512];
    __shared__ float red[8][33];
    __shared__ float osl[32];

    hs[t]       = ws[OFF_HM + (size_t)b * 512 + t];
    hs[t + 256] = ws[OFF_HM + (size_t)b * 512 + t + 256];
    __syncthreads();

    const float* fwp = final_w + (size_t)(dg * 64) * 512 + j;
    const float* hp = hs + dg * 64;
    float acc = 0.f;
    #pragma unroll 8
    for (int d = 0; d < 64; d++)
        acc = fmaf(hp[d], fwp[(size_t)d * 512], acc);
    red[dg][jj] = acc;
    __syncthreads();
    if (t < 32) {
        float s = 0.f;
        #pragma unroll
        for (int q = 0; q < 8; q++) s += red[q][t];
        osl[t] = fmaxf(s + final_b[jt * 32 + t], 0.f);
    }
    __syncthreads();
    if (t < 96) {
        const int l = t >> 5, j2 = t & 31;
        float val = osl[j2] * fc_w[(jt * 32 + j2) * 3 + l];
        #pragma unroll
        for (int off = 16; off > 0; off >>= 1)
            val += __shfl_xor(val, off);
        if (j2 == 0) atomicAdd(out + b * 3 + l, val);
    }
    if (jt == 0 && t < 3) atomicAdd(out + b * 3 + t, fc_b[t]);
}

// ---------------------------------------------------------------------------
extern "C" void kernel_launch(void* const* d_in, const int* in_sizes, int n_in,
                              void* d_out, int out_size, void* d_ws, size_t ws_size,
                              hipStream_t stream)
{
    const float* word    = (const float*)d_in[0];
    const float* rel     = (const float*)d_in[1];
    const float* mask    = (const float*)d_in[2];
    const float* Wn_w    = (const float*)d_in[3];
    const float* Wn_b    = (const float*)d_in[4];
    const float* Wr_w    = (const float*)d_in[5];
    const float* Wr_b    = (const float*)d_in[6];
    const float* lin_w   = (const float*)d_in[7];
    const float* lin_b   = (const float*)d_in[8];
    const float* score_w = (const float*)d_in[9];
    // d_in[10] score_b: cancels in softmax — unused
    const float* final_w = (const float*)d_in[11];
    const float* final_b = (const float*)d_in[12];
    const float* fc_w    = (const float*)d_in[13];
    const float* fc_b    = (const float*)d_in[14];
    float* ws  = (float*)d_ws;
    float* out = (float*)d_out;

    // logits are accumulated atomically -> zero the 192-byte output
    hipMemsetAsync(out, 0, 16 * 3 * sizeof(float), stream);

    proj_gemm<<<392, 256, 0, stream>>>(word, rel, Wn_w, Wn_b, Wr_w, Wr_b,
                                       lin_w, score_w, ws);
    scores_sm<<<256, 256, 0, stream>>>(mask, ws);
    gstep_kernel<<<512, 256, 0, stream>>>(ws);
    headmean_kernel<<<256, 256, 0, stream>>>(lin_w, lin_b, ws);
    final_logits<<<256, 256, 0, stream>>>(final_w, final_b, fc_w, fc_b, ws, out);
}